// Round 5
// baseline (240.732 us; speedup 1.0000x reference)
//
#include <hip/hip_runtime.h>
#include <cstdint>

#define PI_F 3.14159265358979323846f

// ===========================================================================
// Compile-time reproduction of np.random.RandomState(seed).standard_normal
// (MT19937 + legacy Marsaglia polar gauss), packed EXACTLY as round 3's
// host-side g_stage (which passed): cg[966] in cg_off layout repacked per
// block, tabC[133] = u|v<<4|x<<8, tabD[133*4] = {goff|len<<16, doff, p1, p2}.
// ===========================================================================
namespace cgc {

constexpr double csqrt(double x) {
  if (x <= 0.0) return 0.0;
  double m = x; int e = 0;
  while (m >= 4.0) { m *= 0.25; e++; }
  while (m < 1.0) { m *= 4.0; e--; }
  double g = 1.5;
  for (int i = 0; i < 16; i++) g = 0.5 * (g + m / g);
  double s = g;
  if (e > 0) for (int i = 0; i < e; i++) s *= 2.0;
  else       for (int i = 0; i < -e; i++) s *= 0.5;
  return s;
}

constexpr double clog(double x) {
  int k = 0;
  double m = x;
  while (m < 0.7071067811865476) { m *= 2.0; k--; }
  while (m > 1.4142135623730951) { m *= 0.5; k++; }
  double t = (m - 1.0) / (m + 1.0), t2 = t * t, s = 0.0, p = t;
  for (int i = 0; i < 27; i++) { s += p / (double)(2 * i + 1); p *= t2; }
  return 2.0 * s + (double)k * 0.6931471805599453;
}

struct RS { uint32_t mt[624]; int mti; bool has; double g; };

constexpr void rs_seed(RS& r, uint32_t s) {
  for (int i = 0; i < 624; i++) { r.mt[i] = s; s = 1812433253u * (s ^ (s >> 30)) + (uint32_t)i + 1u; }
  r.mti = 624; r.has = false; r.g = 0.0;
}
constexpr uint32_t rs_next(RS& r) {
  if (r.mti >= 624) {
    for (int i = 0; i < 624; i++) {
      uint32_t y = (r.mt[i] & 0x80000000u) | (r.mt[(i + 1) % 624] & 0x7fffffffu);
      r.mt[i] = r.mt[(i + 397) % 624] ^ (y >> 1) ^ ((y & 1u) ? 0x9908b0dfu : 0u);
    }
    r.mti = 0;
  }
  uint32_t y = r.mt[r.mti++];
  y ^= y >> 11; y ^= (y << 7) & 0x9d2c5680u; y ^= (y << 15) & 0xefc60000u; y ^= y >> 18;
  return y;
}
constexpr double rs_dbl(RS& r) {
  uint32_t a = rs_next(r) >> 5, b = rs_next(r) >> 6;
  return ((double)a * 67108864.0 + (double)b) / 9007199254740992.0;
}
constexpr double rs_gauss(RS& r) {
  if (r.has) { r.has = false; return r.g; }
  double x1 = 0, x2 = 0, r2 = 0;
  do {
    x1 = 2.0 * rs_dbl(r) - 1.0;
    x2 = 2.0 * rs_dbl(r) - 1.0;
    r2 = x1 * x1 + x2 * x2;
  } while (r2 >= 1.0 || r2 == 0.0);
  double f = csqrt(-2.0 * clog(r2) / r2);
  r.g = f * x1; r.has = true;
  return f * x2;
}

struct Tab { float v[228]; };

constexpr Tab gen(int l1, int l2, int l3) {
  Tab t{};
  RS r{};
  rs_seed(r, (uint32_t)(1000 + l1 * 100 + l2 * 10 + l3));
  int sz = (2 * l1 + 1) * (2 * l2 + 1) * (2 * l3 + 1);
  for (int k = 0; k < sz; k++) t.v[k] = (float)rs_gauss(r);
  return t;
}

// one constexpr-evaluation budget per table
constexpr Tab T000 = gen(0,0,0);
constexpr Tab T101 = gen(1,0,1);
constexpr Tab T110 = gen(1,1,0);
constexpr Tab T111 = gen(1,1,1);
constexpr Tab T112 = gen(1,1,2);
constexpr Tab T202 = gen(2,0,2);
constexpr Tab T211 = gen(2,1,1);
constexpr Tab T212 = gen(2,1,2);
constexpr Tab T213 = gen(2,1,3);
constexpr Tab T220 = gen(2,2,0);
constexpr Tab T221 = gen(2,2,1);
constexpr Tab T222 = gen(2,2,2);
constexpr Tab T223 = gen(2,2,3);
constexpr Tab T224 = gen(2,2,4);

struct alignas(16) Stage {
  int tabD[133 * 4];   // goff|len<<16, doff, p1, p2  (16B-aligned, offset 0)
  float cg[966];
  uint32_t tabC[133];  // u | v<<4 | x<<8
};

constexpr Stage make_stage() {
  Stage S{};
  const Tab* tabs[14] = {&T000,&T101,&T110,&T111,&T112,&T202,&T211,&T212,&T213,
                         &T220,&T221,&T222,&T223,&T224};
  const int KL[14][3] = {{0,0,0},{1,0,1},{1,1,0},{1,1,1},{1,1,2},{2,0,2},{2,1,1},
                         {2,1,2},{2,1,3},{2,2,0},{2,2,1},{2,2,2},{2,2,3},{2,2,4}};
  const int kBk[6][2] = {{0,0},{1,0},{1,1},{2,0},{2,1},{2,2}};

  int cgbase[6] = {}, dbase[6] = {}, xlenA[6] = {};
  int off = 0, doff = 0;
  for (int bk = 0; bk < 6; bk++) {
    int l1 = kBk[bk][0], l2 = kBk[bk][1];
    int M = 2 * l1 + 1, N = 2 * l2 + 1;
    int Ar = (l1 == 0) ? 3 : (l1 == 1) ? 2 : 1;
    int Br = (l2 == 0) ? 3 : (l2 == 1) ? 2 : 1;
    int xs[25] = {}, xl3[25] = {}, xa[25] = {};
    int cnt = 0;
    for (int l3 = l1 - l2; l3 <= l1 + l2; l3++)
      for (int a = 0; a < 2 * l3 + 1; a++) {
        xs[cnt] = l3 * l3 + a; xl3[cnt] = l3; xa[cnt] = a; cnt++;
      }
    int xlen = cnt;
    xlenA[bk] = xlen; cgbase[bk] = off; dbase[bk] = doff;
    for (int mn = 0; mn < M * N; mn++)
      for (int xi = 0; xi < xlen; xi++) {
        int l3 = xl3[xi], K3 = 2 * l3 + 1, ti = 0;
        for (int c = 0; c < 14; c++)
          if (KL[c][0] == l1 && KL[c][1] == l2 && KL[c][2] == l3) ti = c;
        S.cg[off + mn * xlen + xi] = tabs[ti]->v[mn * K3 + xa[xi]];
      }
    off += M * N * xlen;
    for (int q = 0; q < Ar * Br; q++) {
      int a = q / Br, b = q % Br;
      int u = (l1 == 0) ? a : (l1 == 1) ? 3 + a : 5;
      int v = (l2 == 0) ? b : (l2 == 1) ? 3 + b : 5;
      for (int xi = 0; xi < xlen; xi++)
        S.tabC[doff + q * xlen + xi] = (uint32_t)(u | (v << 4) | (xs[xi] << 8));
    }
    doff += Ar * Br * xlen;
  }
  // tabD, blocks sorted big-first for strip balance (round 3 order)
  const int ord[6] = {5, 4, 2, 3, 1, 0};
  int ei = 0;
  for (int bo = 0; bo < 6; bo++) {
    int bk = ord[bo];
    int l1 = kBk[bk][0], l2 = kBk[bk][1];
    int M = 2 * l1 + 1, N = 2 * l2 + 1;
    int Ar = (l1 == 0) ? 3 : (l1 == 1) ? 2 : 1;
    int Br = (l2 == 0) ? 3 : (l2 == 1) ? 2 : 1;
    int rb1 = (l1 == 0) ? 0 : (l1 == 1) ? 3 : 9;
    int rb2 = (l2 == 0) ? 0 : (l2 == 1) ? 3 : 9;
    int colDim = N * Br, xlen = xlenA[bk];
    for (int e = 0; e < M * N * Ar * Br; e++) {
      int b = e % Br, t2 = e / Br;
      int a = t2 % Ar; t2 /= Ar;
      int n = t2 % N, m = t2 / N;
      int mn = m * N + n, q = a * Br + b;
      int ri = e / colDim, ci = e % colDim;
      int p1 = (rb1 + ri) * 14 + (rb2 + ci);
      int p2 = (l1 == l2) ? p1 : ((rb2 + ci) * 14 + (rb1 + ri));
      S.tabD[4 * ei + 0] = (cgbase[bk] + mn * xlen) | (xlen << 16);
      S.tabD[4 * ei + 1] = dbase[bk] + q * xlen;
      S.tabD[4 * ei + 2] = p1;
      S.tabD[4 * ei + 3] = p2;
      ei++;
    }
  }
  return S;
}

constexpr Stage ST = make_stage();

}  // namespace cgc

__device__ const cgc::Stage g_tab = cgc::ST;

// ===========================================================================
// Kernel: round 3's passing kernel VERBATIM, except tables come from g_tab
// instead of d_ws (no memcpy node in the graph).
// ===========================================================================
#define PSTRIDE 536  // 400 regionA + 136 regionB

__global__ __launch_bounds__(256, 4) void outlayer_kernel(
    const float* __restrict__ c0, const float* __restrict__ c1,
    const float* __restrict__ c2, const float* __restrict__ c3,
    const float* __restrict__ c4, const float* __restrict__ R,
    const float* __restrict__ w_rad, const float* __restrict__ weight,
    const float* __restrict__ s_colg, const float* __restrict__ p_colg,
    const float* __restrict__ d_colg, const int* __restrict__ Z,
    const int* __restrict__ api, const int* __restrict__ aidx,
    float* __restrict__ out) {
  __shared__ float s_wrad[2560];
  __shared__ float s_cg[966];
  __shared__ float s_w6[36 * 17];  // coll_u*coll_v products, stride-17 pad
  __shared__ float s_buf[16 * PSTRIDE];

  const int tid = threadIdx.x;

#pragma unroll
  for (int t = 0; t < 10; t++) s_wrad[tid + t * 256] = w_rad[tid + t * 256];
  for (int e = tid; e < 966; e += 256) s_cg[e] = g_tab.cg[e];
  for (int idx = tid; idx < 576; idx += 256) {
    int comb = idx >> 4, f = idx & 15;
    int u = comb / 6, v = comb % 6;
    float cu = (u < 3) ? s_colg[u * 16 + f] : (u < 5) ? p_colg[(u - 3) * 16 + f] : d_colg[f];
    float cv = (v < 3) ? s_colg[v * 16 + f] : (v < 5) ? p_colg[(v - 3) * 16 + f] : d_colg[f];
    s_w6[comb * 17 + f] = cu * cv;
  }
  __syncthreads();

  const int grp = tid >> 4;
  const int lane = tid & 15;
  const int p = blockIdx.x * 16 + grp;  // P = 50000 = 3125*16 exactly
  float* sb = s_buf + grp * PSTRIDE;
  float* sbD = sb + 400;

  const int i = api[2 * p], j = api[2 * p + 1];
  const int ai = aidx[p];
  const int t1 = Z[api[2 * ai]], t2 = Z[api[2 * ai + 1]];

  // --- radial basis ---
  float dx = R[3 * i + 0] - R[3 * j + 0];
  float dy = R[3 * i + 1] - R[3 * j + 1];
  float dz = R[3 * i + 2] - R[3 * j + 2];
  float d = sqrtf(dx * dx + dy * dy + dz * dz);
  float env = 0.0f;
  if (d < 5.0f) env = 0.5f * (cosf(PI_F * d * 0.2f) + 1.0f);
  float th = PI_F * d * 0.2f;
  float rlo = sinf((float)(lane + 1) * th) * env;
  float rhi = sinf((float)(lane + 17) * th) * env;

  // g[l][f=lane]
  float gl[5] = {0.f, 0.f, 0.f, 0.f, 0.f};
#pragma unroll
  for (int k = 0; k < 16; k++) {
    float rv = __shfl(rlo, k, 16);
#pragma unroll
    for (int l = 0; l < 5; l++) gl[l] += rv * s_wrad[l * 512 + k * 16 + lane];
  }
#pragma unroll
  for (int k = 0; k < 16; k++) {
    float rv = __shfl(rhi, k, 16);
#pragma unroll
    for (int l = 0; l < 5; l++) gl[l] += rv * s_wrad[l * 512 + (k + 16) * 16 + lane];
  }

  // --- Phase A: h[l][m][c] = g[l][c]*(c_l[i,c,m]+c_l[j,c,m]) -> regionA
  const float* cl[5] = {c0, c1, c2, c3, c4};
#pragma unroll
  for (int l = 0; l < 5; l++) {
    const int nm = 2 * l + 1;
    const float* ci = cl[l] + (size_t)i * 16 * nm;
    const float* cj = cl[l] + (size_t)j * 16 * nm;
#pragma unroll
    for (int t = 0; t < 2 * l + 1; t++) {
      int flat = t * 16 + lane;          // coalesced over lanes
      int f = flat / nm, m = flat - f * nm;
      float gf = __shfl(gl[l], f, 16);
      sb[16 * l * l + m * 16 + f] = gf * (ci[flat] + cj[flat]);
    }
  }
  __syncthreads();

  // --- Phase B: co[x=l^2+m] = sum_c gw[lane][c] * h[l][m][c]
  float co[25];
#pragma unroll
  for (int x = 0; x < 25; x++) co[x] = 0.f;
  const float* w1 = weight + (size_t)(t1 * 10 + t2) * 1280 + lane * 16;
  const float* w2 = weight + (size_t)(t2 * 10 + t1) * 1280 + lane * 16;
#pragma unroll
  for (int l = 0; l < 5; l++) {
    float gwreg[16];
#pragma unroll
    for (int cq = 0; cq < 4; cq++) {
      float4 a4 = *(const float4*)(w1 + l * 256 + cq * 4);
      float4 b4 = *(const float4*)(w2 + l * 256 + cq * 4);
      gwreg[cq * 4 + 0] = a4.x + b4.x;
      gwreg[cq * 4 + 1] = a4.y + b4.y;
      gwreg[cq * 4 + 2] = a4.z + b4.z;
      gwreg[cq * 4 + 3] = a4.w + b4.w;
    }
#pragma unroll
    for (int m = 0; m < 2 * l + 1; m++) {
      const float* hb = &sb[16 * l * l + m * 16];
      float acc = co[l * l + m];
#pragma unroll
      for (int cq = 0; cq < 4; cq++) {
        float4 h4 = *(const float4*)(hb + cq * 4);  // broadcast within group
        acc += gwreg[cq * 4 + 0] * h4.x + gwreg[cq * 4 + 1] * h4.y +
               gwreg[cq * 4 + 2] * h4.z + gwreg[cq * 4 + 3] * h4.w;
      }
      co[l * l + m] = acc;
    }
  }
  __syncthreads();  // WAR: co overwrite of h region

  // co -> LDS [f*25 + x]
#pragma unroll
  for (int x = 0; x < 25; x++) sb[lane * 25 + x] = co[x];
  __syncthreads();

  // --- Phase C': Dtab[t] = sum_f w_uv[f] * co[f][x]
#pragma unroll
  for (int it = 0; it < 9; it++) {
    int t = it * 16 + lane;
    if (t < 133) {
      int pc = (int)g_tab.tabC[t];
      int u = pc & 15, v = (pc >> 4) & 15, x = pc >> 8;
      const float* wrow = &s_w6[(u * 6 + v) * 17];
      float acc = 0.f;
#pragma unroll
      for (int f = 0; f < 16; f++) acc += wrow[f] * sb[f * 25 + x];
      sbD[t] = acc;
    }
  }
  __syncthreads();

  // --- Phase D': out element = CG row . Dtab slice -> out_stage (regionA)
#pragma unroll
  for (int it = 0; it < 9; it++) {
    int t = it * 16 + lane;
    if (t < 133) {
      int4 td = ((const int4*)g_tab.tabD)[t];
      int goff = td.x & 0xffff, len = td.x >> 16, doff = td.y;
      float acc = 0.f;
      for (int xi = 0; xi < len; xi++) acc += s_cg[goff + xi] * sbD[doff + xi];
      sb[td.z] = acc;
      sb[td.w] = acc;  // transpose copy (== td.z for diagonal blocks)
    }
  }
  __syncthreads();

  // --- coalesced float4 writeout of the staged 196 floats
  float* outp = out + (size_t)p * 196;
#pragma unroll
  for (int r = 0; r < 4; r++) {
    int idx = r * 16 + lane;
    if (idx < 49) {
      float4 v = *(const float4*)&sb[idx * 4];
      *(float4*)(outp + idx * 4) = v;
    }
  }
}

// ===========================================================================
// Launch: single kernel, no host work, no workspace, no memcpy.
// ===========================================================================
extern "C" void kernel_launch(void* const* d_in, const int* in_sizes, int n_in,
                              void* d_out, int out_size, void* d_ws, size_t ws_size,
                              hipStream_t stream) {
  (void)in_sizes; (void)n_in; (void)out_size; (void)d_ws; (void)ws_size;

  const float* c0 = (const float*)d_in[0];
  const float* c1 = (const float*)d_in[1];
  const float* c2 = (const float*)d_in[2];
  const float* c3 = (const float*)d_in[3];
  const float* c4 = (const float*)d_in[4];
  const float* R = (const float*)d_in[5];
  const float* w_rad = (const float*)d_in[6];
  const float* weight = (const float*)d_in[7];
  const float* s_col = (const float*)d_in[8];
  const float* p_col = (const float*)d_in[9];
  const float* d_col = (const float*)d_in[10];
  const int* Z = (const int*)d_in[11];
  const int* api = (const int*)d_in[12];
  const int* aidx = (const int*)d_in[13];

  dim3 grid(3125), block(256);
  hipLaunchKernelGGL(outlayer_kernel, grid, block, 0, stream,
                     c0, c1, c2, c3, c4, R, w_rad, weight, s_col, p_col, d_col,
                     Z, api, aidx, (float*)d_out);
}

// Round 6
// 186.224 us; speedup vs baseline: 1.2927x; 1.2927x over previous
//
#include <hip/hip_runtime.h>
#include <cstdint>

#define PI_F 3.14159265358979323846f

// ===========================================================================
// Compile-time reproduction of np.random.RandomState(seed).standard_normal
// (MT19937 + legacy Marsaglia polar gauss), packed as round 3/5's verified
// layout: cg[966] repacked per block, tabC[133] = u|v<<4|x<<8,
// tabD[133*4] = {goff|len<<16, doff, p1, p2}.
// ===========================================================================
namespace cgc {

constexpr double csqrt(double x) {
  if (x <= 0.0) return 0.0;
  double m = x; int e = 0;
  while (m >= 4.0) { m *= 0.25; e++; }
  while (m < 1.0) { m *= 4.0; e--; }
  double g = 1.5;
  for (int i = 0; i < 16; i++) g = 0.5 * (g + m / g);
  double s = g;
  if (e > 0) for (int i = 0; i < e; i++) s *= 2.0;
  else       for (int i = 0; i < -e; i++) s *= 0.5;
  return s;
}

constexpr double clog(double x) {
  int k = 0;
  double m = x;
  while (m < 0.7071067811865476) { m *= 2.0; k--; }
  while (m > 1.4142135623730951) { m *= 0.5; k++; }
  double t = (m - 1.0) / (m + 1.0), t2 = t * t, s = 0.0, p = t;
  for (int i = 0; i < 27; i++) { s += p / (double)(2 * i + 1); p *= t2; }
  return 2.0 * s + (double)k * 0.6931471805599453;
}

struct RS { uint32_t mt[624]; int mti; bool has; double g; };

constexpr void rs_seed(RS& r, uint32_t s) {
  for (int i = 0; i < 624; i++) { r.mt[i] = s; s = 1812433253u * (s ^ (s >> 30)) + (uint32_t)i + 1u; }
  r.mti = 624; r.has = false; r.g = 0.0;
}
constexpr uint32_t rs_next(RS& r) {
  if (r.mti >= 624) {
    for (int i = 0; i < 624; i++) {
      uint32_t y = (r.mt[i] & 0x80000000u) | (r.mt[(i + 1) % 624] & 0x7fffffffu);
      r.mt[i] = r.mt[(i + 397) % 624] ^ (y >> 1) ^ ((y & 1u) ? 0x9908b0dfu : 0u);
    }
    r.mti = 0;
  }
  uint32_t y = r.mt[r.mti++];
  y ^= y >> 11; y ^= (y << 7) & 0x9d2c5680u; y ^= (y << 15) & 0xefc60000u; y ^= y >> 18;
  return y;
}
constexpr double rs_dbl(RS& r) {
  uint32_t a = rs_next(r) >> 5, b = rs_next(r) >> 6;
  return ((double)a * 67108864.0 + (double)b) / 9007199254740992.0;
}
constexpr double rs_gauss(RS& r) {
  if (r.has) { r.has = false; return r.g; }
  double x1 = 0, x2 = 0, r2 = 0;
  do {
    x1 = 2.0 * rs_dbl(r) - 1.0;
    x2 = 2.0 * rs_dbl(r) - 1.0;
    r2 = x1 * x1 + x2 * x2;
  } while (r2 >= 1.0 || r2 == 0.0);
  double f = csqrt(-2.0 * clog(r2) / r2);
  r.g = f * x1; r.has = true;
  return f * x2;
}

struct Tab { float v[228]; };

constexpr Tab gen(int l1, int l2, int l3) {
  Tab t{};
  RS r{};
  rs_seed(r, (uint32_t)(1000 + l1 * 100 + l2 * 10 + l3));
  int sz = (2 * l1 + 1) * (2 * l2 + 1) * (2 * l3 + 1);
  for (int k = 0; k < sz; k++) t.v[k] = (float)rs_gauss(r);
  return t;
}

constexpr Tab T000 = gen(0,0,0);
constexpr Tab T101 = gen(1,0,1);
constexpr Tab T110 = gen(1,1,0);
constexpr Tab T111 = gen(1,1,1);
constexpr Tab T112 = gen(1,1,2);
constexpr Tab T202 = gen(2,0,2);
constexpr Tab T211 = gen(2,1,1);
constexpr Tab T212 = gen(2,1,2);
constexpr Tab T213 = gen(2,1,3);
constexpr Tab T220 = gen(2,2,0);
constexpr Tab T221 = gen(2,2,1);
constexpr Tab T222 = gen(2,2,2);
constexpr Tab T223 = gen(2,2,3);
constexpr Tab T224 = gen(2,2,4);

struct alignas(16) Stage {
  int tabD[133 * 4];   // goff|len<<16, doff, p1, p2
  float cg[966];
  uint32_t tabC[133];  // u | v<<4 | x<<8
};

constexpr Stage make_stage() {
  Stage S{};
  const Tab* tabs[14] = {&T000,&T101,&T110,&T111,&T112,&T202,&T211,&T212,&T213,
                         &T220,&T221,&T222,&T223,&T224};
  const int KL[14][3] = {{0,0,0},{1,0,1},{1,1,0},{1,1,1},{1,1,2},{2,0,2},{2,1,1},
                         {2,1,2},{2,1,3},{2,2,0},{2,2,1},{2,2,2},{2,2,3},{2,2,4}};
  const int kBk[6][2] = {{0,0},{1,0},{1,1},{2,0},{2,1},{2,2}};

  int cgbase[6] = {}, dbase[6] = {}, xlenA[6] = {};
  int off = 0, doff = 0;
  for (int bk = 0; bk < 6; bk++) {
    int l1 = kBk[bk][0], l2 = kBk[bk][1];
    int M = 2 * l1 + 1, N = 2 * l2 + 1;
    int Ar = (l1 == 0) ? 3 : (l1 == 1) ? 2 : 1;
    int Br = (l2 == 0) ? 3 : (l2 == 1) ? 2 : 1;
    int xs[25] = {}, xl3[25] = {}, xa[25] = {};
    int cnt = 0;
    for (int l3 = l1 - l2; l3 <= l1 + l2; l3++)
      for (int a = 0; a < 2 * l3 + 1; a++) {
        xs[cnt] = l3 * l3 + a; xl3[cnt] = l3; xa[cnt] = a; cnt++;
      }
    int xlen = cnt;
    xlenA[bk] = xlen; cgbase[bk] = off; dbase[bk] = doff;
    for (int mn = 0; mn < M * N; mn++)
      for (int xi = 0; xi < xlen; xi++) {
        int l3 = xl3[xi], K3 = 2 * l3 + 1, ti = 0;
        for (int c = 0; c < 14; c++)
          if (KL[c][0] == l1 && KL[c][1] == l2 && KL[c][2] == l3) ti = c;
        S.cg[off + mn * xlen + xi] = tabs[ti]->v[mn * K3 + xa[xi]];
      }
    off += M * N * xlen;
    for (int q = 0; q < Ar * Br; q++) {
      int a = q / Br, b = q % Br;
      int u = (l1 == 0) ? a : (l1 == 1) ? 3 + a : 5;
      int v = (l2 == 0) ? b : (l2 == 1) ? 3 + b : 5;
      for (int xi = 0; xi < xlen; xi++)
        S.tabC[doff + q * xlen + xi] = (uint32_t)(u | (v << 4) | (xs[xi] << 8));
    }
    doff += Ar * Br * xlen;
  }
  const int ord[6] = {5, 4, 2, 3, 1, 0};  // big xlen first
  int ei = 0;
  for (int bo = 0; bo < 6; bo++) {
    int bk = ord[bo];
    int l1 = kBk[bk][0], l2 = kBk[bk][1];
    int M = 2 * l1 + 1, N = 2 * l2 + 1;
    int Ar = (l1 == 0) ? 3 : (l1 == 1) ? 2 : 1;
    int Br = (l2 == 0) ? 3 : (l2 == 1) ? 2 : 1;
    int rb1 = (l1 == 0) ? 0 : (l1 == 1) ? 3 : 9;
    int rb2 = (l2 == 0) ? 0 : (l2 == 1) ? 3 : 9;
    int colDim = N * Br, xlen = xlenA[bk];
    for (int e = 0; e < M * N * Ar * Br; e++) {
      int b = e % Br, t2 = e / Br;
      int a = t2 % Ar; t2 /= Ar;
      int n = t2 % N, m = t2 / N;
      int mn = m * N + n, q = a * Br + b;
      int ri = e / colDim, ci = e % colDim;
      int p1 = (rb1 + ri) * 14 + (rb2 + ci);
      int p2 = (l1 == l2) ? p1 : ((rb2 + ci) * 14 + (rb1 + ri));
      S.tabD[4 * ei + 0] = (cgbase[bk] + mn * xlen) | (xlen << 16);
      S.tabD[4 * ei + 1] = dbase[bk] + q * xlen;
      S.tabD[4 * ei + 2] = p1;
      S.tabD[4 * ei + 3] = p2;
      ei++;
    }
  }
  return S;
}

constexpr Stage ST = make_stage();

}  // namespace cgc

__device__ const cgc::Stage g_tab = cgc::ST;

// ===========================================================================
// Kernel: r5 base + (1) phase-A f=lane reassignment (no div/shfl, conflict-
// free writes), (2) co layout [x*16+f] + float4 C', (3) tabC/tabD in LDS,
// (4) __sinf/__cosf. D' and phase B unchanged from the verified r5.
// ===========================================================================
#define PSTRIDE 536  // 400 regionA + 136 regionB

__global__ __launch_bounds__(256, 4) void outlayer_kernel(
    const float* __restrict__ c0, const float* __restrict__ c1,
    const float* __restrict__ c2, const float* __restrict__ c3,
    const float* __restrict__ c4, const float* __restrict__ R,
    const float* __restrict__ w_rad, const float* __restrict__ weight,
    const float* __restrict__ s_colg, const float* __restrict__ p_colg,
    const float* __restrict__ d_colg, const int* __restrict__ Z,
    const int* __restrict__ api, const int* __restrict__ aidx,
    float* __restrict__ out) {
  __shared__ float s_wrad[2560];
  __shared__ __align__(16) float s_cg[966];
  __shared__ __align__(16) float s_w6[36 * 16];  // coll_u*coll_v per f
  __shared__ __align__(16) float s_buf[16 * PSTRIDE];
  __shared__ int s_tabC[133];
  __shared__ __align__(16) int4 s_tabD[133];

  const int tid = threadIdx.x;

  // ---- stage constants ----
#pragma unroll
  for (int t = 0; t < 10; t++) s_wrad[tid + t * 256] = w_rad[tid + t * 256];
  for (int e = tid; e < 966; e += 256) s_cg[e] = g_tab.cg[e];
  for (int e = tid; e < 133; e += 256) {
    s_tabC[e] = (int)g_tab.tabC[e];
    s_tabD[e] = ((const int4*)g_tab.tabD)[e];
  }
  for (int idx = tid; idx < 576; idx += 256) {
    int comb = idx >> 4, f = idx & 15;
    int u = comb / 6, v = comb % 6;
    float cu = (u < 3) ? s_colg[u * 16 + f] : (u < 5) ? p_colg[(u - 3) * 16 + f] : d_colg[f];
    float cv = (v < 3) ? s_colg[v * 16 + f] : (v < 5) ? p_colg[(v - 3) * 16 + f] : d_colg[f];
    s_w6[comb * 16 + f] = cu * cv;
  }
  __syncthreads();

  const int grp = tid >> 4;
  const int lane = tid & 15;            // feature index f
  const int p = blockIdx.x * 16 + grp;  // P = 50000 = 3125*16 exactly
  float* sb = s_buf + grp * PSTRIDE;
  float* sbD = sb + 400;

  const int i = api[2 * p], j = api[2 * p + 1];
  const int ai = aidx[p];
  const int t1 = Z[api[2 * ai]], t2 = Z[api[2 * ai + 1]];

  // ---- radial basis ----
  float dx = R[3 * i + 0] - R[3 * j + 0];
  float dy = R[3 * i + 1] - R[3 * j + 1];
  float dz = R[3 * i + 2] - R[3 * j + 2];
  float d = sqrtf(dx * dx + dy * dy + dz * dz);
  float env = 0.0f;
  if (d < 5.0f) env = 0.5f * (__cosf(PI_F * d * 0.2f) + 1.0f);
  float th = PI_F * d * 0.2f;
  float rlo = __sinf((float)(lane + 1) * th) * env;   // rbf[lane]
  float rhi = __sinf((float)(lane + 17) * th) * env;  // rbf[lane+16]

  // g[l][f=lane] = sum_k rbf[k] * w_rad[l,k,f]   (all lanes active -> shfl safe)
  float gl[5] = {0.f, 0.f, 0.f, 0.f, 0.f};
#pragma unroll
  for (int k = 0; k < 16; k++) {
    float rv = __shfl(rlo, k, 16);
#pragma unroll
    for (int l = 0; l < 5; l++) gl[l] += rv * s_wrad[l * 512 + k * 16 + lane];
  }
#pragma unroll
  for (int k = 0; k < 16; k++) {
    float rv = __shfl(rhi, k, 16);
#pragma unroll
    for (int l = 0; l < 5; l++) gl[l] += rv * s_wrad[l * 512 + (k + 16) * 16 + lane];
  }

  // ---- Phase A: h[m][f=lane] = g[l][lane]*(ci[lane,m]+cj[lane,m]) ----
  // store addr = m*16+lane -> consecutive banks across lanes (conflict-free)
  const float* cl[5] = {c0, c1, c2, c3, c4};
#pragma unroll
  for (int l = 0; l < 5; l++) {
    const int nm = 2 * l + 1;
    const float* ci = cl[l] + ((size_t)i * 16 + lane) * nm;
    const float* cj = cl[l] + ((size_t)j * 16 + lane) * nm;
    float* hb = sb + 16 * l * l;
#pragma unroll
    for (int m = 0; m < 2 * l + 1; m++)
      hb[m * 16 + lane] = gl[l] * (ci[m] + cj[m]);
  }
  __syncthreads();

  // ---- Phase B: co[x=l^2+m] = sum_c gw[lane][c] * h[m][c] (unchanged) ----
  float co[25];
#pragma unroll
  for (int x = 0; x < 25; x++) co[x] = 0.f;
  const float* w1 = weight + (size_t)(t1 * 10 + t2) * 1280 + lane * 16;
  const float* w2 = weight + (size_t)(t2 * 10 + t1) * 1280 + lane * 16;
#pragma unroll
  for (int l = 0; l < 5; l++) {
    float gwreg[16];
#pragma unroll
    for (int cq = 0; cq < 4; cq++) {
      float4 a4 = *(const float4*)(w1 + l * 256 + cq * 4);
      float4 b4 = *(const float4*)(w2 + l * 256 + cq * 4);
      gwreg[cq * 4 + 0] = a4.x + b4.x;
      gwreg[cq * 4 + 1] = a4.y + b4.y;
      gwreg[cq * 4 + 2] = a4.z + b4.z;
      gwreg[cq * 4 + 3] = a4.w + b4.w;
    }
#pragma unroll
    for (int m = 0; m < 2 * l + 1; m++) {
      const float* hb = &sb[16 * l * l + m * 16];
      float acc = co[l * l + m];
#pragma unroll
      for (int cq = 0; cq < 4; cq++) {
        float4 h4 = *(const float4*)(hb + cq * 4);  // broadcast within group
        acc += gwreg[cq * 4 + 0] * h4.x + gwreg[cq * 4 + 1] * h4.y +
               gwreg[cq * 4 + 2] * h4.z + gwreg[cq * 4 + 3] * h4.w;
      }
      co[l * l + m] = acc;
    }
  }
  __syncthreads();  // WAR: co store overwrites h region

  // co -> LDS [x*16 + f]  (max 24*16+15 = 399, fits regionA)
#pragma unroll
  for (int x = 0; x < 25; x++) sb[x * 16 + lane] = co[x];
  __syncthreads();

  // ---- Phase C': Dtab[t] = sum_f w_uv[f] * co[f][x]  (float4 LDS reads) ----
#pragma unroll
  for (int it = 0; it < 9; it++) {
    int t = it * 16 + lane;
    if (t < 133) {
      int pc = s_tabC[t];
      int u = pc & 15, v = (pc >> 4) & 15, x = pc >> 8;
      const float* wrow = &s_w6[(u * 6 + v) * 16];
      float acc = 0.f;
#pragma unroll
      for (int q = 0; q < 4; q++) {
        float4 wv = *(const float4*)&wrow[q * 4];
        float4 cv = *(const float4*)&sb[x * 16 + q * 4];
        acc += wv.x * cv.x + wv.y * cv.y + wv.z * cv.z + wv.w * cv.w;
      }
      sbD[t] = acc;
    }
  }
  __syncthreads();

  // ---- Phase D': out elem = cg row . Dtab slice -> out stage (regionA) ----
#pragma unroll
  for (int it = 0; it < 9; it++) {
    int t = it * 16 + lane;
    if (t < 133) {
      int4 td = s_tabD[t];
      int goff = td.x & 0xffff, len = td.x >> 16, doff = td.y;
      float acc = 0.f;
      for (int xi = 0; xi < len; xi++) acc += s_cg[goff + xi] * sbD[doff + xi];
      sb[td.z] = acc;
      sb[td.w] = acc;  // transpose copy (== td.z on diagonal blocks)
    }
  }
  __syncthreads();

  // ---- coalesced float4 writeout of the staged 196 floats ----
  float* outp = out + (size_t)p * 196;
#pragma unroll
  for (int r = 0; r < 4; r++) {
    int idx = r * 16 + lane;
    if (idx < 49) {
      float4 v = *(const float4*)&sb[idx * 4];
      *(float4*)(outp + idx * 4) = v;
    }
  }
}

// ===========================================================================
// Launch: single kernel, no host work, no workspace, no memcpy.
// ===========================================================================
extern "C" void kernel_launch(void* const* d_in, const int* in_sizes, int n_in,
                              void* d_out, int out_size, void* d_ws, size_t ws_size,
                              hipStream_t stream) {
  (void)in_sizes; (void)n_in; (void)out_size; (void)d_ws; (void)ws_size;

  const float* c0 = (const float*)d_in[0];
  const float* c1 = (const float*)d_in[1];
  const float* c2 = (const float*)d_in[2];
  const float* c3 = (const float*)d_in[3];
  const float* c4 = (const float*)d_in[4];
  const float* R = (const float*)d_in[5];
  const float* w_rad = (const float*)d_in[6];
  const float* weight = (const float*)d_in[7];
  const float* s_col = (const float*)d_in[8];
  const float* p_col = (const float*)d_in[9];
  const float* d_col = (const float*)d_in[10];
  const int* Z = (const int*)d_in[11];
  const int* api = (const int*)d_in[12];
  const int* aidx = (const int*)d_in[13];

  dim3 grid(3125), block(256);
  hipLaunchKernelGGL(outlayer_kernel, grid, block, 0, stream,
                     c0, c1, c2, c3, c4, R, w_rad, weight, s_col, p_col, d_col,
                     Z, api, aidx, (float*)d_out);
}

// Round 7
// 182.190 us; speedup vs baseline: 1.3213x; 1.0221x over previous
//
#include <hip/hip_runtime.h>
#include <cstdint>

#define PI_F 3.14159265358979323846f

// ===========================================================================
// Compile-time reproduction of np.random.RandomState(seed).standard_normal
// (MT19937 + legacy Marsaglia polar gauss), packed as the verified r5/r6
// layout: cg[966] repacked per block, tabC[133] = u|v<<4|x<<8,
// tabD[133*4] = {goff|len<<16, doff, p1, p2}.
// ===========================================================================
namespace cgc {

constexpr double csqrt(double x) {
  if (x <= 0.0) return 0.0;
  double m = x; int e = 0;
  while (m >= 4.0) { m *= 0.25; e++; }
  while (m < 1.0) { m *= 4.0; e--; }
  double g = 1.5;
  for (int i = 0; i < 16; i++) g = 0.5 * (g + m / g);
  double s = g;
  if (e > 0) for (int i = 0; i < e; i++) s *= 2.0;
  else       for (int i = 0; i < -e; i++) s *= 0.5;
  return s;
}

constexpr double clog(double x) {
  int k = 0;
  double m = x;
  while (m < 0.7071067811865476) { m *= 2.0; k--; }
  while (m > 1.4142135623730951) { m *= 0.5; k++; }
  double t = (m - 1.0) / (m + 1.0), t2 = t * t, s = 0.0, p = t;
  for (int i = 0; i < 27; i++) { s += p / (double)(2 * i + 1); p *= t2; }
  return 2.0 * s + (double)k * 0.6931471805599453;
}

struct RS { uint32_t mt[624]; int mti; bool has; double g; };

constexpr void rs_seed(RS& r, uint32_t s) {
  for (int i = 0; i < 624; i++) { r.mt[i] = s; s = 1812433253u * (s ^ (s >> 30)) + (uint32_t)i + 1u; }
  r.mti = 624; r.has = false; r.g = 0.0;
}
constexpr uint32_t rs_next(RS& r) {
  if (r.mti >= 624) {
    for (int i = 0; i < 624; i++) {
      uint32_t y = (r.mt[i] & 0x80000000u) | (r.mt[(i + 1) % 624] & 0x7fffffffu);
      r.mt[i] = r.mt[(i + 397) % 624] ^ (y >> 1) ^ ((y & 1u) ? 0x9908b0dfu : 0u);
    }
    r.mti = 0;
  }
  uint32_t y = r.mt[r.mti++];
  y ^= y >> 11; y ^= (y << 7) & 0x9d2c5680u; y ^= (y << 15) & 0xefc60000u; y ^= y >> 18;
  return y;
}
constexpr double rs_dbl(RS& r) {
  uint32_t a = rs_next(r) >> 5, b = rs_next(r) >> 6;
  return ((double)a * 67108864.0 + (double)b) / 9007199254740992.0;
}
constexpr double rs_gauss(RS& r) {
  if (r.has) { r.has = false; return r.g; }
  double x1 = 0, x2 = 0, r2 = 0;
  do {
    x1 = 2.0 * rs_dbl(r) - 1.0;
    x2 = 2.0 * rs_dbl(r) - 1.0;
    r2 = x1 * x1 + x2 * x2;
  } while (r2 >= 1.0 || r2 == 0.0);
  double f = csqrt(-2.0 * clog(r2) / r2);
  r.g = f * x1; r.has = true;
  return f * x2;
}

struct Tab { float v[228]; };

constexpr Tab gen(int l1, int l2, int l3) {
  Tab t{};
  RS r{};
  rs_seed(r, (uint32_t)(1000 + l1 * 100 + l2 * 10 + l3));
  int sz = (2 * l1 + 1) * (2 * l2 + 1) * (2 * l3 + 1);
  for (int k = 0; k < sz; k++) t.v[k] = (float)rs_gauss(r);
  return t;
}

constexpr Tab T000 = gen(0,0,0);
constexpr Tab T101 = gen(1,0,1);
constexpr Tab T110 = gen(1,1,0);
constexpr Tab T111 = gen(1,1,1);
constexpr Tab T112 = gen(1,1,2);
constexpr Tab T202 = gen(2,0,2);
constexpr Tab T211 = gen(2,1,1);
constexpr Tab T212 = gen(2,1,2);
constexpr Tab T213 = gen(2,1,3);
constexpr Tab T220 = gen(2,2,0);
constexpr Tab T221 = gen(2,2,1);
constexpr Tab T222 = gen(2,2,2);
constexpr Tab T223 = gen(2,2,3);
constexpr Tab T224 = gen(2,2,4);

struct alignas(16) Stage {
  int tabD[133 * 4];   // goff|len<<16, doff, p1, p2
  float cg[966];
  uint32_t tabC[133];  // u | v<<4 | x<<8
};

constexpr Stage make_stage() {
  Stage S{};
  const Tab* tabs[14] = {&T000,&T101,&T110,&T111,&T112,&T202,&T211,&T212,&T213,
                         &T220,&T221,&T222,&T223,&T224};
  const int KL[14][3] = {{0,0,0},{1,0,1},{1,1,0},{1,1,1},{1,1,2},{2,0,2},{2,1,1},
                         {2,1,2},{2,1,3},{2,2,0},{2,2,1},{2,2,2},{2,2,3},{2,2,4}};
  const int kBk[6][2] = {{0,0},{1,0},{1,1},{2,0},{2,1},{2,2}};

  int cgbase[6] = {}, dbase[6] = {}, xlenA[6] = {};
  int off = 0, doff = 0;
  for (int bk = 0; bk < 6; bk++) {
    int l1 = kBk[bk][0], l2 = kBk[bk][1];
    int M = 2 * l1 + 1, N = 2 * l2 + 1;
    int Ar = (l1 == 0) ? 3 : (l1 == 1) ? 2 : 1;
    int Br = (l2 == 0) ? 3 : (l2 == 1) ? 2 : 1;
    int xs[25] = {}, xl3[25] = {}, xa[25] = {};
    int cnt = 0;
    for (int l3 = l1 - l2; l3 <= l1 + l2; l3++)
      for (int a = 0; a < 2 * l3 + 1; a++) {
        xs[cnt] = l3 * l3 + a; xl3[cnt] = l3; xa[cnt] = a; cnt++;
      }
    int xlen = cnt;
    xlenA[bk] = xlen; cgbase[bk] = off; dbase[bk] = doff;
    for (int mn = 0; mn < M * N; mn++)
      for (int xi = 0; xi < xlen; xi++) {
        int l3 = xl3[xi], K3 = 2 * l3 + 1, ti = 0;
        for (int c = 0; c < 14; c++)
          if (KL[c][0] == l1 && KL[c][1] == l2 && KL[c][2] == l3) ti = c;
        S.cg[off + mn * xlen + xi] = tabs[ti]->v[mn * K3 + xa[xi]];
      }
    off += M * N * xlen;
    for (int q = 0; q < Ar * Br; q++) {
      int a = q / Br, b = q % Br;
      int u = (l1 == 0) ? a : (l1 == 1) ? 3 + a : 5;
      int v = (l2 == 0) ? b : (l2 == 1) ? 3 + b : 5;
      for (int xi = 0; xi < xlen; xi++)
        S.tabC[doff + q * xlen + xi] = (uint32_t)(u | (v << 4) | (xs[xi] << 8));
    }
    doff += Ar * Br * xlen;
  }
  const int ord[6] = {5, 4, 2, 3, 1, 0};  // big xlen first
  int ei = 0;
  for (int bo = 0; bo < 6; bo++) {
    int bk = ord[bo];
    int l1 = kBk[bk][0], l2 = kBk[bk][1];
    int M = 2 * l1 + 1, N = 2 * l2 + 1;
    int Ar = (l1 == 0) ? 3 : (l1 == 1) ? 2 : 1;
    int Br = (l2 == 0) ? 3 : (l2 == 1) ? 2 : 1;
    int rb1 = (l1 == 0) ? 0 : (l1 == 1) ? 3 : 9;
    int rb2 = (l2 == 0) ? 0 : (l2 == 1) ? 3 : 9;
    int colDim = N * Br, xlen = xlenA[bk];
    for (int e = 0; e < M * N * Ar * Br; e++) {
      int b = e % Br, t2 = e / Br;
      int a = t2 % Ar; t2 /= Ar;
      int n = t2 % N, m = t2 / N;
      int mn = m * N + n, q = a * Br + b;
      int ri = e / colDim, ci = e % colDim;
      int p1 = (rb1 + ri) * 14 + (rb2 + ci);
      int p2 = (l1 == l2) ? p1 : ((rb2 + ci) * 14 + (rb1 + ri));
      S.tabD[4 * ei + 0] = (cgbase[bk] + mn * xlen) | (xlen << 16);
      S.tabD[4 * ei + 1] = dbase[bk] + q * xlen;
      S.tabD[4 * ei + 2] = p1;
      S.tabD[4 * ei + 3] = p2;
      ei++;
    }
  }
  return S;
}

constexpr Stage ST = make_stage();

}  // namespace cgc

__device__ const cgc::Stage g_tab = cgc::ST;

// ===========================================================================
// Kernel: r6 base + (1) all inter-phase __syncthreads removed — every
// per-pair LDS region is wave-local (16-lane group inside one wave; LDS ops
// within a wave are in program order), wave_barrier() as scheduling fence;
// (2) chunk-rotation swizzle on co rows and w6 rows so phase-C' b128 reads
// spread over 8 bank-quads (was 2 -> 8-way conflict).
// ===========================================================================
#define PSTRIDE 536  // 400 regionA + 136 regionB

__global__ __launch_bounds__(256, 4) void outlayer_kernel(
    const float* __restrict__ c0, const float* __restrict__ c1,
    const float* __restrict__ c2, const float* __restrict__ c3,
    const float* __restrict__ c4, const float* __restrict__ R,
    const float* __restrict__ w_rad, const float* __restrict__ weight,
    const float* __restrict__ s_colg, const float* __restrict__ p_colg,
    const float* __restrict__ d_colg, const int* __restrict__ Z,
    const int* __restrict__ api, const int* __restrict__ aidx,
    float* __restrict__ out) {
  __shared__ float s_wrad[2560];
  __shared__ __align__(16) float s_cg[966];
  __shared__ __align__(16) float s_w6[36 * 16];  // chunk-rotated by comb
  __shared__ __align__(16) float s_buf[16 * PSTRIDE];
  __shared__ int s_tabC[133];
  __shared__ __align__(16) int4 s_tabD[133];

  const int tid = threadIdx.x;

  // ---- stage constants ----
#pragma unroll
  for (int t = 0; t < 10; t++) s_wrad[tid + t * 256] = w_rad[tid + t * 256];
  for (int e = tid; e < 966; e += 256) s_cg[e] = g_tab.cg[e];
  for (int e = tid; e < 133; e += 256) {
    s_tabC[e] = (int)g_tab.tabC[e];
    s_tabD[e] = ((const int4*)g_tab.tabD)[e];
  }
  for (int idx = tid; idx < 576; idx += 256) {
    int comb = idx >> 4, f = idx & 15;
    int u = comb / 6, v = comb % 6;
    float cu = (u < 3) ? s_colg[u * 16 + f] : (u < 5) ? p_colg[(u - 3) * 16 + f] : d_colg[f];
    float cv = (v < 3) ? s_colg[v * 16 + f] : (v < 5) ? p_colg[(v - 3) * 16 + f] : d_colg[f];
    s_w6[comb * 16 + ((f + 4 * (comb >> 1)) & 15)] = cu * cv;  // chunk-rotate
  }
  __syncthreads();  // the only block-wide barrier: constants shared by all waves

  const int grp = tid >> 4;
  const int lane = tid & 15;            // feature index f
  const int p = blockIdx.x * 16 + grp;  // P = 50000 = 3125*16 exactly
  float* sb = s_buf + grp * PSTRIDE;    // per-pair region, wave-local
  float* sbD = sb + 400;

  const int i = api[2 * p], j = api[2 * p + 1];
  const int ai = aidx[p];
  const int t1 = Z[api[2 * ai]], t2 = Z[api[2 * ai + 1]];

  // ---- radial basis ----
  float dx = R[3 * i + 0] - R[3 * j + 0];
  float dy = R[3 * i + 1] - R[3 * j + 1];
  float dz = R[3 * i + 2] - R[3 * j + 2];
  float d = sqrtf(dx * dx + dy * dy + dz * dz);
  float env = 0.0f;
  if (d < 5.0f) env = 0.5f * (__cosf(PI_F * d * 0.2f) + 1.0f);
  float th = PI_F * d * 0.2f;
  float rlo = __sinf((float)(lane + 1) * th) * env;   // rbf[lane]
  float rhi = __sinf((float)(lane + 17) * th) * env;  // rbf[lane+16]

  // g[l][f=lane] = sum_k rbf[k] * w_rad[l,k,f]   (all lanes active -> shfl safe)
  float gl[5] = {0.f, 0.f, 0.f, 0.f, 0.f};
#pragma unroll
  for (int k = 0; k < 16; k++) {
    float rv = __shfl(rlo, k, 16);
#pragma unroll
    for (int l = 0; l < 5; l++) gl[l] += rv * s_wrad[l * 512 + k * 16 + lane];
  }
#pragma unroll
  for (int k = 0; k < 16; k++) {
    float rv = __shfl(rhi, k, 16);
#pragma unroll
    for (int l = 0; l < 5; l++) gl[l] += rv * s_wrad[l * 512 + (k + 16) * 16 + lane];
  }

  // ---- Phase A: h[m][f=lane] = g[l][lane]*(ci[lane,m]+cj[lane,m]) ----
  const float* cl[5] = {c0, c1, c2, c3, c4};
#pragma unroll
  for (int l = 0; l < 5; l++) {
    const int nm = 2 * l + 1;
    const float* ci = cl[l] + ((size_t)i * 16 + lane) * nm;
    const float* cj = cl[l] + ((size_t)j * 16 + lane) * nm;
    float* hb = sb + 16 * l * l;
#pragma unroll
    for (int m = 0; m < 2 * l + 1; m++)
      hb[m * 16 + lane] = gl[l] * (ci[m] + cj[m]);
  }
  __builtin_amdgcn_wave_barrier();  // wave-local ordering fence (no-op inst)

  // ---- Phase B: co[x=l^2+m] = sum_c gw[lane][c] * h[m][c] ----
  float co[25];
#pragma unroll
  for (int x = 0; x < 25; x++) co[x] = 0.f;
  const float* w1 = weight + (size_t)(t1 * 10 + t2) * 1280 + lane * 16;
  const float* w2 = weight + (size_t)(t2 * 10 + t1) * 1280 + lane * 16;
#pragma unroll
  for (int l = 0; l < 5; l++) {
    float gwreg[16];
#pragma unroll
    for (int cq = 0; cq < 4; cq++) {
      float4 a4 = *(const float4*)(w1 + l * 256 + cq * 4);
      float4 b4 = *(const float4*)(w2 + l * 256 + cq * 4);
      gwreg[cq * 4 + 0] = a4.x + b4.x;
      gwreg[cq * 4 + 1] = a4.y + b4.y;
      gwreg[cq * 4 + 2] = a4.z + b4.z;
      gwreg[cq * 4 + 3] = a4.w + b4.w;
    }
#pragma unroll
    for (int m = 0; m < 2 * l + 1; m++) {
      const float* hb = &sb[16 * l * l + m * 16];
      float acc = co[l * l + m];
#pragma unroll
      for (int cq = 0; cq < 4; cq++) {
        float4 h4 = *(const float4*)(hb + cq * 4);  // broadcast within group
        acc += gwreg[cq * 4 + 0] * h4.x + gwreg[cq * 4 + 1] * h4.y +
               gwreg[cq * 4 + 2] * h4.z + gwreg[cq * 4 + 3] * h4.w;
      }
      co[l * l + m] = acc;
    }
  }
  __builtin_amdgcn_wave_barrier();  // reads of h complete (in-order) before overwrite

  // co -> LDS, chunk-rotated by (x>>1): element f at [x*16 + ((f+4*(x>>1))&15)]
#pragma unroll
  for (int x = 0; x < 25; x++) sb[x * 16 + ((lane + 4 * (x >> 1)) & 15)] = co[x];
  __builtin_amdgcn_wave_barrier();

  // ---- Phase C': Dtab[t] = sum_f w_uv[f] * co[f][x]  (swizzled b128 reads) ----
#pragma unroll
  for (int it = 0; it < 9; it++) {
    int t = it * 16 + lane;
    if (t < 133) {
      int pc = s_tabC[t];
      int u = pc & 15, v = (pc >> 4) & 15, x = pc >> 8;
      int comb = u * 6 + v;
      int rotW = 4 * (comb >> 1), rotC = 4 * (x >> 1);
      const float* wrow = &s_w6[comb * 16];
      const float* crow = &sb[x * 16];
      float acc = 0.f;
#pragma unroll
      for (int q = 0; q < 4; q++) {
        float4 wv = *(const float4*)&wrow[(4 * q + rotW) & 15];
        float4 cv = *(const float4*)&crow[(4 * q + rotC) & 15];
        acc += wv.x * cv.x + wv.y * cv.y + wv.z * cv.z + wv.w * cv.w;
      }
      sbD[t] = acc;
    }
  }
  __builtin_amdgcn_wave_barrier();

  // ---- Phase D': out elem = cg row . Dtab slice -> out stage (regionA) ----
#pragma unroll
  for (int it = 0; it < 9; it++) {
    int t = it * 16 + lane;
    if (t < 133) {
      int4 td = s_tabD[t];
      int goff = td.x & 0xffff, len = td.x >> 16, doff = td.y;
      float acc = 0.f;
      for (int xi = 0; xi < len; xi++) acc += s_cg[goff + xi] * sbD[doff + xi];
      sb[td.z] = acc;
      sb[td.w] = acc;  // transpose copy (== td.z on diagonal blocks)
    }
  }
  __builtin_amdgcn_wave_barrier();

  // ---- coalesced float4 writeout of the staged 196 floats ----
  float* outp = out + (size_t)p * 196;
#pragma unroll
  for (int r = 0; r < 4; r++) {
    int idx = r * 16 + lane;
    if (idx < 49) {
      float4 v = *(const float4*)&sb[idx * 4];
      *(float4*)(outp + idx * 4) = v;
    }
  }
}

// ===========================================================================
// Launch: single kernel, no host work, no workspace, no memcpy.
// ===========================================================================
extern "C" void kernel_launch(void* const* d_in, const int* in_sizes, int n_in,
                              void* d_out, int out_size, void* d_ws, size_t ws_size,
                              hipStream_t stream) {
  (void)in_sizes; (void)n_in; (void)out_size; (void)d_ws; (void)ws_size;

  const float* c0 = (const float*)d_in[0];
  const float* c1 = (const float*)d_in[1];
  const float* c2 = (const float*)d_in[2];
  const float* c3 = (const float*)d_in[3];
  const float* c4 = (const float*)d_in[4];
  const float* R = (const float*)d_in[5];
  const float* w_rad = (const float*)d_in[6];
  const float* weight = (const float*)d_in[7];
  const float* s_col = (const float*)d_in[8];
  const float* p_col = (const float*)d_in[9];
  const float* d_col = (const float*)d_in[10];
  const int* Z = (const int*)d_in[11];
  const int* api = (const int*)d_in[12];
  const int* aidx = (const int*)d_in[13];

  dim3 grid(3125), block(256);
  hipLaunchKernelGGL(outlayer_kernel, grid, block, 0, stream,
                     c0, c1, c2, c3, c4, R, w_rad, weight, s_col, p_col, d_col,
                     Z, api, aidx, (float*)d_out);
}